// Round 1
// baseline (240.763 us; speedup 1.0000x reference)
//
#include <hip/hip_runtime.h>
#include <math.h>

#define B_ 64
#define N_ 200
#define P_ 400
#define T_ 1200
#define NW_ 48        // T / STRIDE
#define STRIDE_ 25
#define EPS_ 1e-9f

// ws layout (float offsets)
#define OFF_NPATT  0            // [N_][P_] transposed normalized patterns (80000)
#define OFF_KEYVAL 80000        // [P_][4] top-3 signed values (pad 1)
#define OFF_KEYIDX 81600        // [P_][4] top-3 indices (int)
#define OFF_PES    83200        // [B_][P_]
#define OFF_NORM   108800       // scalar accum
#define OFF_ORTH   108801       // scalar accum

// ---------------- pattern preprocessing: normalize rows, top-3, norm scalar ----
__global__ __launch_bounds__(64) void pat_kernel(const float* __restrict__ patterns,
                                                 float* __restrict__ ws) {
    int p = blockIdx.x;
    int lane = threadIdx.x;

    // N_=200 -> lane, lane+64, lane+128 always valid; lane+192 valid for lane<8
    float v0 = patterns[p * N_ + lane];
    float v1 = patterns[p * N_ + lane + 64];
    float v2 = patterns[p * N_ + lane + 128];
    float v3 = (lane < 8) ? patterns[p * N_ + lane + 192] : 0.0f;

    float ss = v0 * v0 + v1 * v1 + v2 * v2 + v3 * v3;
    for (int off = 32; off; off >>= 1) ss += __shfl_down(ss, off);
    ss = __shfl(ss, 0);

    float rn = 1.0f / sqrtf(ss + EPS_);
    float s0 = v0 * rn, s1 = v1 * rn, s2 = v2 * rn, s3 = v3 * rn;

    float* npatT = ws + OFF_NPATT;
    npatT[(lane) * P_ + p] = s0;
    npatT[(lane + 64) * P_ + p] = s1;
    npatT[(lane + 128) * P_ + p] = s2;
    if (lane < 8) npatT[(lane + 192) * P_ + p] = s3;

    float a0 = fabsf(s0), a1 = fabsf(s1), a2 = fabsf(s2);
    float a3 = fabsf(s3);

    int ch0 = -1, ch1 = -1, ch2 = -1;
    float cs0 = 0.f, cs1 = 0.f, cs2 = 0.f;

    for (int r = 0; r < 3; r++) {
        float bv = -1.0f;
        int bi = 1 << 30;
        {
            int n = lane;
            bool sk = (n == ch0) || (n == ch1) || (n == ch2);
            if (!sk && a0 > bv) { bv = a0; bi = n; }
        }
        {
            int n = lane + 64;
            bool sk = (n == ch0) || (n == ch1) || (n == ch2);
            if (!sk && (a1 > bv || (a1 == bv && n < bi))) { bv = a1; bi = n; }
        }
        {
            int n = lane + 128;
            bool sk = (n == ch0) || (n == ch1) || (n == ch2);
            if (!sk && (a2 > bv || (a2 == bv && n < bi))) { bv = a2; bi = n; }
        }
        if (lane < 8) {
            int n = lane + 192;
            bool sk = (n == ch0) || (n == ch1) || (n == ch2);
            if (!sk && (a3 > bv || (a3 == bv && n < bi))) { bv = a3; bi = n; }
        }
        // wave argmax (tie -> lower index, matches top_k stability)
        for (int off = 32; off; off >>= 1) {
            float ov = __shfl_down(bv, off);
            int oi = __shfl_down(bi, off);
            if (ov > bv || (ov == bv && oi < bi)) { bv = ov; bi = oi; }
        }
        bi = __shfl(bi, 0);
        // gather signed value from owning lane
        int slot = bi >> 6, src = bi & 63;
        float mine = (slot == 0) ? s0 : (slot == 1) ? s1 : (slot == 2) ? s2 : s3;
        float sval = __shfl(mine, src);
        if (r == 0) { ch0 = bi; cs0 = sval; }
        else if (r == 1) { ch1 = bi; cs1 = sval; }
        else { ch2 = bi; cs2 = sval; }
    }

    if (lane == 0) {
        float* keyval = ws + OFF_KEYVAL;
        int* keyidx = (int*)(ws + OFF_KEYIDX);
        keyval[p * 4 + 0] = cs0; keyval[p * 4 + 1] = cs1; keyval[p * 4 + 2] = cs2;
        keyidx[p * 4 + 0] = ch0; keyidx[p * 4 + 1] = ch1; keyidx[p * 4 + 2] = ch2;
        float lenp = sqrtf(ss) * rn;                       // ||normalized row||
        float lentopp = sqrtf(cs0 * cs0 + cs1 * cs1 + cs2 * cs2);
        float d = 1.0f - lentopp / lenp;
        atomicAdd(ws + OFF_NORM, d * d * (1.0f / (float)P_));
    }
}

// ---------------- orth regularizer: simpp = npat @ npat^T ----------------------
__global__ __launch_bounds__(256) void orth_kernel(float* __restrict__ ws) {
    __shared__ float rowi[N_];
    __shared__ float red[256];
    const float* npatT = ws + OFF_NPATT;
    int i = blockIdx.x;
    for (int k = threadIdx.x; k < N_; k += 256) rowi[k] = npatT[k * P_ + i];
    __syncthreads();

    float partial = 0.0f;
    for (int j = threadIdx.x; j < P_; j += 256) {
        if (j == i) continue;
        float s = 0.0f;
        for (int k = 0; k < N_; k++) s += rowi[k] * npatT[k * P_ + j];
        float t = (fabsf(s) - 0.3f) * (1.0f / 0.70001f);
        if (t > 0.0f) partial += t * t;
    }
    red[threadIdx.x] = partial;
    __syncthreads();
    for (int sft = 128; sft; sft >>= 1) {
        if (threadIdx.x < sft) red[threadIdx.x] += red[threadIdx.x + sft];
        __syncthreads();
    }
    if (threadIdx.x == 0)
        atomicAdd(ws + OFF_ORTH, red[0] * (1.0f / ((float)P_ * (float)P_)));
}

// ---------------- fused GEMM + window pooling -> PES ---------------------------
// block = (window w, batch b); computes sim for 25 frames x 400 patterns,
// pos/neg max over the window, atomically adds (pos+neg)/(2*sap) into PES.
__global__ __launch_bounds__(256) void main_kernel(const float* __restrict__ x,
                                                   const int* __restrict__ length,
                                                   const float* __restrict__ ws,
                                                   float* __restrict__ pes) {
    __shared__ float xs[N_][STRIDE_ + 1];     // [200][26]
    __shared__ float rnorm[STRIDE_];
    __shared__ float poolp[P_][5];
    __shared__ float pooln[P_][5];

    int w = blockIdx.x;
    int b = blockIdx.y;
    const float* xb = x + (size_t)b * N_ * T_ + (size_t)w * STRIDE_;

    for (int i = threadIdx.x; i < N_ * STRIDE_; i += 256) {
        int n = i / STRIDE_;
        int t = i - n * STRIDE_;
        xs[n][t] = xb[n * T_ + t];
    }
    __syncthreads();

    if (threadIdx.x < STRIDE_) {
        float ssf = 0.0f;
        for (int n = 0; n < N_; n++) { float vv = xs[n][threadIdx.x]; ssf += vv * vv; }
        rnorm[threadIdx.x] = 1.0f / sqrtf(ssf + EPS_);
    }
    __syncthreads();

    int pt = threadIdx.x % 50;   // 50 p-groups of 8
    int tt = threadIdx.x / 50;   // 5 t-groups of 5 (tt==5 idle)

    if (tt < 5) {
        float acc[8][5];
#pragma unroll
        for (int i = 0; i < 8; i++)
#pragma unroll
            for (int j = 0; j < 5; j++) acc[i][j] = 0.0f;

        const float4* np4 = (const float4*)(ws + OFF_NPATT);
        int pb = pt * 2;
        for (int n = 0; n < N_; n++) {
            float4 q0 = np4[n * (P_ / 4) + pb];
            float4 q1 = np4[n * (P_ / 4) + pb + 1];
            float qa[8] = { q0.x, q0.y, q0.z, q0.w, q1.x, q1.y, q1.z, q1.w };
            float xv0 = xs[n][tt * 5 + 0];
            float xv1 = xs[n][tt * 5 + 1];
            float xv2 = xs[n][tt * 5 + 2];
            float xv3 = xs[n][tt * 5 + 3];
            float xv4 = xs[n][tt * 5 + 4];
#pragma unroll
            for (int i = 0; i < 8; i++) {
                acc[i][0] += qa[i] * xv0;
                acc[i][1] += qa[i] * xv1;
                acc[i][2] += qa[i] * xv2;
                acc[i][3] += qa[i] * xv3;
                acc[i][4] += qa[i] * xv4;
            }
        }
#pragma unroll
        for (int i = 0; i < 8; i++) {
            float pm = -1e30f, nm = -1e30f;
#pragma unroll
            for (int j = 0; j < 5; j++) {
                float s = acc[i][j] * rnorm[tt * 5 + j];
                pm = fmaxf(pm, s);
                nm = fmaxf(nm, -s);
            }
            poolp[pt * 8 + i][tt] = pm;
            pooln[pt * 8 + i][tt] = nm;
        }
    }
    __syncthreads();

    float rsap = 1.0f / (float)(length[b] / STRIDE_);   // floor(len/25), len>=500
    for (int p = threadIdx.x; p < P_; p += 256) {
        float pm = poolp[p][0], nm = pooln[p][0];
#pragma unroll
        for (int q = 1; q < 5; q++) {
            pm = fmaxf(pm, poolp[p][q]);
            nm = fmaxf(nm, pooln[p][q]);
        }
        atomicAdd(&pes[b * P_ + p], (pm + nm) * 0.5f * rsap);
    }
}

// ---------------- sparse graphs assembly + scalar outputs ----------------------
__global__ __launch_bounds__(256) void graphs_kernel(const float* __restrict__ ws,
                                                     float* __restrict__ out) {
    int idx = blockIdx.x * 256 + threadIdx.x;
    if (idx == 0) {
        out[(size_t)B_ * N_ * N_] = ws[OFF_NORM];
        out[(size_t)B_ * N_ * N_ + 1] = ws[OFF_ORTH];
    }
    if (idx >= B_ * P_) return;
    int b = idx / P_;
    int p = idx - b * P_;

    float e = ws[OFF_PES + b * P_ + p];
    const float* keyval = ws + OFF_KEYVAL;
    const int* keyidx = (const int*)(ws + OFF_KEYIDX);
    float va[3] = { keyval[p * 4 + 0], keyval[p * 4 + 1], keyval[p * 4 + 2] };
    int ia[3] = { keyidx[p * 4 + 0], keyidx[p * 4 + 1], keyidx[p * 4 + 2] };

    float* g = out + (size_t)b * N_ * N_;
#pragma unroll
    for (int a = 0; a < 3; a++) {
#pragma unroll
        for (int c = 0; c < 3; c++) {
            float scale = (ia[a] == ia[c]) ? 1.0f : 6.0f;   // diag vs off-diag (c=6)
            atomicAdd(&g[ia[a] * N_ + ia[c]], va[a] * va[c] * e * scale);
        }
    }
}

extern "C" void kernel_launch(void* const* d_in, const int* in_sizes, int n_in,
                              void* d_out, int out_size, void* d_ws, size_t ws_size,
                              hipStream_t stream) {
    const float* x = (const float*)d_in[0];
    const float* patterns = (const float*)d_in[1];
    const int* length = (const int*)d_in[2];
    float* out = (float*)d_out;
    float* ws = (float*)d_ws;

    // zero PES + norm/orth accumulators, and the graphs output region
    hipMemsetAsync(ws + OFF_PES, 0, (size_t)(B_ * P_ + 2) * sizeof(float), stream);
    hipMemsetAsync(d_out, 0, (size_t)B_ * N_ * N_ * sizeof(float), stream);

    pat_kernel<<<P_, 64, 0, stream>>>(patterns, ws);
    orth_kernel<<<P_, 256, 0, stream>>>(ws);
    main_kernel<<<dim3(NW_, B_), 256, 0, stream>>>(x, length, ws, ws + OFF_PES);
    graphs_kernel<<<(B_ * P_ + 255) / 256, 256, 0, stream>>>(ws, out);
}